// Round 1
// 901.113 us; speedup vs baseline: 1.1797x; 1.1797x over previous
//
#include <hip/hip_runtime.h>
#include <math.h>

// ---------------------------------------------------------------------------
// AtomicHAR pipeline. fp32 everywhere except the post-selection ad2 GEMM
// (bf16 MFMA — cannot affect segment selection; tolerance 9.9e-2 vs ~3e-3 err).
// bs=128 seq=128 C=6 L=20 N=16384 D=64 H=256 MAL=10 Wtot=1280
// ---------------------------------------------------------------------------

#define NWIN 16384   // bs*seq
#define SEQ  128
#define BS   128
#define KSEL 3276    // int(16384*0.2)
#define SEGSTRIDE 160    // worst-case segments per batch ~140
#define RECCAP 18432     // worst-case total segments

typedef __attribute__((ext_vector_type(8))) short short8v;
typedef __attribute__((ext_vector_type(4))) float float4v;

__device__ inline unsigned short bf16rne(float f) {
    unsigned u = __float_as_uint(f);
    unsigned r = u + 0x7FFFu + ((u >> 16) & 1u);
    return (unsigned short)(r >> 16);
}

// ---------------- fused encoder: conv1+pool, conv2+pool, conv3+pool, bridge --
__global__ __launch_bounds__(256) void k_encoder(
        const float* __restrict__ x,
        const float* __restrict__ c1w, const float* __restrict__ c1b,
        const float* __restrict__ c2w, const float* __restrict__ c2b,
        const float* __restrict__ c3w, const float* __restrict__ c3b,
        const float* __restrict__ brw, const float* __restrict__ brb,
        float* __restrict__ bridge, float* __restrict__ out_resh,
        float* __restrict__ out_fin) {
    __shared__ float c1wt[288];    // (ic*3+dk)*16 + oc
    __shared__ float c2wt[1536];   // (ic*3+dk)*32 + oc
    __shared__ float c3wt[3072];   // (ic*3+dk)*32 + oc
    __shared__ float brws[4096];   // i*64 + d
    __shared__ float c1bs[16], c2bs[32], c3bs[32], brbs[64];
    __shared__ float xs[4][128], c1s[4][160], c2s[4][160], c3s[4][64];

    int tid = threadIdx.x;
    for (int i = tid; i < 288; i += 256) {
        int oc = i / 18, r = i - oc * 18, ic = r / 3, dk = r - ic * 3;
        c1wt[(ic * 3 + dk) * 16 + oc] = c1w[i];
    }
    for (int i = tid; i < 1536; i += 256) {
        int oc = i / 48, r = i - oc * 48, ic = r / 3, dk = r - ic * 3;
        c2wt[(ic * 3 + dk) * 32 + oc] = c2w[i];
    }
    for (int i = tid; i < 3072; i += 256) {
        int oc = i / 96, r = i - oc * 96, ic = r / 3, dk = r - ic * 3;
        c3wt[(ic * 3 + dk) * 32 + oc] = c3w[i];
    }
    for (int i = tid; i < 4096; i += 256) brws[i] = brw[i];
    if (tid < 16) c1bs[tid] = c1b[tid];
    else if (tid < 48) c2bs[tid - 16] = c2b[tid - 16];
    else if (tid < 80) c3bs[tid - 48] = c3b[tid - 48];
    else if (tid < 144) brbs[tid - 80] = brb[tid - 80];

    int wv = tid >> 6, lane = tid & 63;
    int n = blockIdx.x * 4 + wv;
    const float* xr = x + (size_t)n * 120;
    if (lane < 60) ((float2*)&xs[wv][0])[lane] = ((const float2*)xr)[lane];
    __syncthreads();

    // conv1
    {
        int oc = lane >> 2, tg = lane & 3;
        float bb = c1bs[oc];
        float acc[3][2];
#pragma unroll
        for (int j = 0; j < 3; ++j) { acc[j][0] = bb; acc[j][1] = bb; }
        for (int ic = 0; ic < 6; ++ic) {
            float w0 = c1wt[(ic * 3 + 0) * 16 + oc];
            float w1 = c1wt[(ic * 3 + 1) * 16 + oc];
            float w2 = c1wt[(ic * 3 + 2) * 16 + oc];
            const float* ar = &xs[wv][ic * 20];
#pragma unroll
            for (int j = 0; j < 3; ++j) {
                int t = tg + 4 * j;
                if (t < 10) {
#pragma unroll
                    for (int q = 0; q < 2; ++q) {
                        int p = 2 * t + q;
                        float a0 = (p >= 1) ? ar[p - 1] : 0.f;
                        float a1 = ar[p];
                        float a2 = (p + 1 < 20) ? ar[p + 1] : 0.f;
                        acc[j][q] += a0 * w0 + a1 * w1 + a2 * w2;
                    }
                }
            }
        }
#pragma unroll
        for (int j = 0; j < 3; ++j) {
            int t = tg + 4 * j;
            if (t < 10) c1s[wv][oc * 10 + t] = fmaxf(fmaxf(acc[j][0], acc[j][1]), 0.f);
        }
    }
    __syncthreads();

    // conv2
    {
        int oc = lane >> 1, tg = lane & 1;
        float bb = c2bs[oc];
        float acc[3][2];
#pragma unroll
        for (int j = 0; j < 3; ++j) { acc[j][0] = bb; acc[j][1] = bb; }
        for (int ic = 0; ic < 16; ++ic) {
            float w0 = c2wt[(ic * 3 + 0) * 32 + oc];
            float w1 = c2wt[(ic * 3 + 1) * 32 + oc];
            float w2 = c2wt[(ic * 3 + 2) * 32 + oc];
            const float* ar = &c1s[wv][ic * 10];
#pragma unroll
            for (int j = 0; j < 3; ++j) {
                int t = tg + 2 * j;
                if (t < 5) {
#pragma unroll
                    for (int q = 0; q < 2; ++q) {
                        int p = 2 * t + q;
                        float a0 = (p >= 1) ? ar[p - 1] : 0.f;
                        float a1 = ar[p];
                        float a2 = (p + 1 < 10) ? ar[p + 1] : 0.f;
                        acc[j][q] += a0 * w0 + a1 * w1 + a2 * w2;
                    }
                }
            }
        }
#pragma unroll
        for (int j = 0; j < 3; ++j) {
            int t = tg + 2 * j;
            if (t < 5) c2s[wv][oc * 5 + t] = fmaxf(fmaxf(acc[j][0], acc[j][1]), 0.f);
        }
    }
    __syncthreads();

    // conv3
    {
        int oc = lane >> 1, tp = lane & 1;
        float bb = c3bs[oc];
        float acc0 = bb, acc1 = bb;
        for (int ic = 0; ic < 32; ++ic) {
            float w0 = c3wt[(ic * 3 + 0) * 32 + oc];
            float w1 = c3wt[(ic * 3 + 1) * 32 + oc];
            float w2 = c3wt[(ic * 3 + 2) * 32 + oc];
            const float* ar = &c2s[wv][ic * 5];
            {
                int p = 2 * tp;
                float a0 = (p >= 1) ? ar[p - 1] : 0.f;
                acc0 += a0 * w0 + ar[p] * w1 + ar[p + 1] * w2;
            }
            {
                int p = 2 * tp + 1;
                acc1 += ar[p - 1] * w0 + ar[p] * w1 + ((p + 1 < 5) ? ar[p + 1] : 0.f) * w2;
            }
        }
        c3s[wv][lane] = fmaxf(fmaxf(acc0, acc1), 0.f);
    }
    __syncthreads();

    // bridge
    {
        float acc = brbs[lane];
        for (int i = 0; i < 64; ++i) acc += c3s[wv][i] * brws[i * 64 + lane];
        float v = 1.f / (1.f + expf(-acc));
        size_t o = (size_t)n * 64 + lane;
        bridge[o] = v; out_resh[o] = v; out_fin[o] = v;
    }
}

__global__ void k_f1(const float* __restrict__ bridge, const float* __restrict__ w,
                     const float* __restrict__ b, float* __restrict__ feat) {
    int n = blockIdx.x, h = threadIdx.x;
    int s = n & (SEQ - 1);
    float acc = b[h];
    if (s > 0) {
        const float* br = bridge + (n - 1) * 64;
        for (int d = 0; d < 64; ++d) acc += br[d] * w[d * 256 + h];
    }
    feat[n * 256 + h] = fmaxf(acc, 0.f);
}

__global__ void k_f2_loss(const float* __restrict__ feat, const float* __restrict__ bridge,
                          const float* __restrict__ w, const float* __restrict__ b,
                          const float* __restrict__ imu_mask,
                          float* __restrict__ out_fc, float* __restrict__ out_fmask,
                          float* __restrict__ out_loss, float* __restrict__ scores) {
    int n = blockIdx.x, d = threadIdx.x;
    const float* fr = feat + n * 256;
    float acc = b[d];
    for (int h = 0; h < 256; ++h) acc += fr[h] * w[h * 64 + d];
    out_fc[n * 64 + d] = acc;
    int s = n & (SEQ - 1);
    float mval = (s == 0) ? 0.f : imu_mask[(size_t)n * 120];
    out_fmask[n * 64 + d] = mval;
    float diff = (acc - bridge[n * 64 + d]) * mval;
    float sq = diff * diff;
#pragma unroll
    for (int off = 32; off; off >>= 1) sq += __shfl_down(sq, off);
    if (d == 0) {
        float loss = sq * (1.f / 64.f);
        out_loss[n] = loss;
        scores[n] = loss * mval;
    }
}

// exact k-th largest via radix select on float bits (scores >= 0). 1 block x 256.
__global__ void k_select(const float* __restrict__ scores, float* __restrict__ cutoff) {
    __shared__ unsigned hist[256];
    __shared__ unsigned sh_prefix;
    __shared__ int sh_k;
    int tid = threadIdx.x;
    if (tid == 0) { sh_prefix = 0u; sh_k = KSEL; }
    __syncthreads();
    for (int shift = 24; shift >= 0; shift -= 8) {
        hist[tid] = 0u;
        __syncthreads();
        unsigned prefix = sh_prefix;
        unsigned pmask = (shift == 24) ? 0u : (0xFFFFFFFFu << (shift + 8));
        for (int i = tid; i < NWIN; i += 256) {
            unsigned u = __float_as_uint(scores[i]);
            if ((u & pmask) == prefix) atomicAdd(&hist[(u >> shift) & 255u], 1u);
        }
        __syncthreads();
        if (tid == 0) {
            int kk = sh_k;
            for (int bin = 255; bin >= 0; --bin) {
                int c = (int)hist[bin];
                if (kk <= c) { sh_prefix = prefix | ((unsigned)bin << shift); sh_k = kk; break; }
                kk -= c;
            }
        }
        __syncthreads();
    }
    if (tid == 0) *cutoff = __uint_as_float(sh_prefix);
}

// per-batch segmentation with gap-fill. 1 block x 128 (thread per batch).
__global__ void k_segments(const float* __restrict__ loss, const float* __restrict__ cutoff_p,
                           int* __restrict__ segs, int* __restrict__ counts) {
    int b = threadIdx.x;
    if (b >= BS) return;
    float cutoff = *cutoff_p;
    int* my = segs + b * SEGSTRIDE;
    int cnt = 0, prev = 0;
    bool has = false;
    for (int s = 0; s < SEQ; ++s) {
        if (loss[b * SEQ + s] > cutoff) {
            if (has) {
                if (s - prev > 10) {
                    my[cnt++] = prev;
                    int cur = prev;
                    while (cur < s) {
                        cur += 10;
                        if (cur >= s) break;
                        my[cnt++] = cur;
                    }
                } else {
                    my[cnt++] = prev;
                }
            }
            has = true; prev = s;
        }
    }
    if (has) my[cnt++] = prev;
    counts[b] = cnt;
}

// prefix-scan counts, emit (b,last,e) records. 1 block x 128.
__global__ void k_emit(const int* __restrict__ counts, const int* __restrict__ segs,
                       int* __restrict__ rec_b, int* __restrict__ rec_last,
                       int* __restrict__ rec_e, int* __restrict__ total_out) {
    __shared__ int offs[BS + 1];
    int tid = threadIdx.x;
    if (tid == 0) {
        int acc = 0;
        for (int b = 0; b < BS; ++b) { offs[b] = acc; acc += counts[b]; }
        offs[BS] = acc;
        *total_out = acc;
        if (acc == 0) { rec_b[0] = 0; rec_last[0] = 0; rec_e[0] = 0; }  // fallback dummy
    }
    __syncthreads();
    int b = tid;
    int o = offs[b], c = counts[b];
    for (int j = 0; j < c; ++j) {
        int idx = o + j;
        if (idx >= RECCAP) break;
        rec_b[idx] = b;
        rec_last[idx] = (j > 0) ? segs[b * SEGSTRIDE + j - 1] : 0;
        rec_e[idx] = segs[b * SEGSTRIDE + j];
    }
}

// imu_atoms + mask: (A, 6, 1280)
__global__ void k_gather_atoms(const int* __restrict__ rec_b, const int* __restrict__ rec_last,
                               const int* __restrict__ rec_e, const float* __restrict__ x,
                               float* __restrict__ out_atoms, float* __restrict__ out_mask, int A) {
    int gid = blockIdx.x * blockDim.x + threadIdx.x;
    if (gid >= A * 7680) return;
    int a = gid / 7680, rem = gid % 7680, c = rem / 1280, wcol = rem % 1280;
    int b = rec_b[a], last = rec_last[a], e = rec_e[a];
    int W = (e - last) * 20;
    int sc = wcol - (1280 - W);
    float v = 0.f, m = 0.f;
    if (sc >= 0 && sc < W) {
        int t = sc / 20, l = sc % 20;
        v = x[((b * SEQ + last + t) * 6 + c) * 20 + l];
        m = 1.f;
    }
    out_atoms[gid] = v;
    out_mask[gid] = m;
}

// ---------------- autoencoder, batched: 8 segments/block, 256 threads -------
// LDS-staged transposed weights; ae1 p-loop register-hoisted; ad1 joint.
__global__ __launch_bounds__(256) void k_ae2(
        const int* __restrict__ rec_b, const int* __restrict__ rec_last,
        const int* __restrict__ rec_e, const float* __restrict__ bridge,
        const float* __restrict__ ae1w, const float* __restrict__ ae1b,
        const float* __restrict__ ae2w, const float* __restrict__ ae2b,
        const float* __restrict__ ae3w, const float* __restrict__ ae3b,
        const float* __restrict__ ad1w, const float* __restrict__ ad1b,
        unsigned short* __restrict__ hd, int A) {
    __shared__ float ae1wt[6144];   // (ic*3+dk)*32 + o   (o<32, ic<64)
    __shared__ float ae2wt[1536];   // (ic*3+dk)*16 + c   (c<16, ic<32)
    __shared__ float ae3ws[2560];   // i*32 + o
    __shared__ float ae1bs[32], ae2bs[16], ae3bs[32];
    __shared__ float af_s[8][640];  // [seg][ic*10+r]
    __shared__ float c1p[8][160];   // pooled+relu ae1 out [seg][o*5+t]
    __shared__ float h2s[8][80];    // [seg][c*5+t]
    __shared__ float embs[32][8];   // [o][seg]

    int tid = threadIdx.x;
    int a0 = blockIdx.x * 8;

    // ---- stage weights (transposed) ----
    for (int i = tid; i < 6144; i += 256) {
        int o = i / 192, r = i - o * 192, ic = r / 3, dk = r - ic * 3;
        ae1wt[(ic * 3 + dk) * 32 + o] = ae1w[i];
    }
    for (int i = tid; i < 1536; i += 256) {
        int c = i / 96, r = i - c * 96, ic = r / 3, dk = r - ic * 3;
        ae2wt[(ic * 3 + dk) * 16 + c] = ae2w[i];
    }
    for (int i = tid; i < 2560; i += 256) ae3ws[i] = ae3w[i];
    if (tid < 32) ae1bs[tid] = ae1b[tid];
    else if (tid < 48) ae2bs[tid - 32] = ae2b[tid - 32];
    else if (tid < 80) ae3bs[tid - 48] = ae3b[tid - 48];

    // ---- gather af from bridge (each wave: its 2 segments) ----
    int wv = tid >> 6, lane = tid & 63;
#pragma unroll
    for (int sg = 0; sg < 2; ++sg) {
        int seg = wv * 2 + sg;
        int ac = a0 + seg; if (ac > A - 1) ac = A - 1;
        int b = rec_b[ac], last = rec_last[ac], e = rec_e[ac];
#pragma unroll
        for (int r = 0; r < 10; ++r) {
            int src = e - 10 + r;
            float v = (src >= last) ? bridge[(size_t)(b * SEQ + src) * 64 + lane] : 0.f;
            af_s[seg][lane * 10 + r] = v;
        }
    }
    __syncthreads();

    // ---- ae1 conv + relu + pool: seg = wv*2 + (lane>>5), o = lane&31 ----
    {
        int seg = wv * 2 + (lane >> 5);
        int o = lane & 31;
        const float* afl = af_s[seg];
        float bb = ae1bs[o];
        float acc[10];
#pragma unroll
        for (int p = 0; p < 10; ++p) acc[p] = bb;
        for (int ic = 0; ic < 64; ++ic) {
            float av[10];
#pragma unroll
            for (int r = 0; r < 10; ++r) av[r] = afl[ic * 10 + r];  // broadcast
            float w0 = ae1wt[(ic * 3 + 0) * 32 + o];
            float w1 = ae1wt[(ic * 3 + 1) * 32 + o];
            float w2 = ae1wt[(ic * 3 + 2) * 32 + o];
            acc[0] += av[0] * w1 + av[1] * w2;
#pragma unroll
            for (int p = 1; p < 9; ++p)
                acc[p] += av[p - 1] * w0 + av[p] * w1 + av[p + 1] * w2;
            acc[9] += av[8] * w0 + av[9] * w1;
        }
#pragma unroll
        for (int t = 0; t < 5; ++t)
            c1p[seg][o * 5 + t] = fmaxf(fmaxf(acc[2 * t], acc[2 * t + 1]), 0.f);
    }
    __syncthreads();

    // ---- ae2 conv + relu: seg = wv*2+(lane>>5); c = (lane&31)>>1, th = lane&1 ----
    {
        int seg = wv * 2 + (lane >> 5);
        int c = (lane & 31) >> 1, th = lane & 1;
        const float* cp = c1p[seg];
        float bb = ae2bs[c];
        float acc2[3] = {bb, bb, bb};
        for (int ic = 0; ic < 32; ++ic) {
            float m[5];
#pragma unroll
            for (int t = 0; t < 5; ++t) m[t] = cp[ic * 5 + t];  // broadcast
            float w0 = ae2wt[(ic * 3 + 0) * 16 + c];
            float w1 = ae2wt[(ic * 3 + 1) * 16 + c];
            float w2 = ae2wt[(ic * 3 + 2) * 16 + c];
#pragma unroll
            for (int j = 0; j < 3; ++j) {
                int t = th + 2 * j;
                if (t < 5) {
                    float am1 = (t > 0) ? m[t - 1] : 0.f;
                    float ap1 = (t < 4) ? m[t + 1] : 0.f;
                    acc2[j] += am1 * w0 + m[t] * w1 + ap1 * w2;
                }
            }
        }
#pragma unroll
        for (int j = 0; j < 3; ++j) {
            int t = th + 2 * j;
            if (t < 5) h2s[seg][c * 5 + t] = fmaxf(acc2[j], 0.f);
        }
    }
    __syncthreads();

    // ---- ae3: emb(32) per seg: seg = wv*2+(lane>>5), o = lane&31 ----
    {
        int seg = wv * 2 + (lane >> 5);
        int o = lane & 31;
        float acc = ae3bs[o];
        const float* hh = h2s[seg];
        for (int i = 0; i < 80; ++i) acc += hh[i] * ae3ws[i * 32 + o];
        embs[o][seg] = acc;   // no relu on emb
    }
    __syncthreads();

    // ---- ad1 joint: thread tid owns output column idx for ALL 8 segs ----
    {
        int idx = tid;
        float bb = ad1b[idx];
        float acc[8];
#pragma unroll
        for (int s = 0; s < 8; ++s) acc[s] = bb;
        for (int o = 0; o < 32; ++o) {
            float wq = ad1w[o * 256 + idx];   // coalesced, reused 8x
#pragma unroll
            for (int s = 0; s < 8; ++s) acc[s] += embs[o][s] * wq;
        }
#pragma unroll
        for (int s = 0; s < 8; ++s) {
            int a = a0 + s;
            if (a < A) hd[(size_t)a * 256 + idx] = bf16rne(fmaxf(acc[s], 0.f));
        }
    }
}

// transpose + bf16-cast ad2_w (256 x 7680, row-major) -> wbT (7680 x 256, n-major)
__global__ __launch_bounds__(256) void k_wtrans(const float* __restrict__ w,
                                                unsigned short* __restrict__ wbT) {
    __shared__ float tile[64][65];
    int n0 = blockIdx.x * 64, k0 = blockIdx.y * 64;
    int tid = threadIdx.x;
    int c = tid & 63;
    for (int r = tid >> 6; r < 64; r += 4)
        tile[r][c] = w[(size_t)(k0 + r) * 7680 + n0 + c];
    __syncthreads();
    int n = tid >> 4, kq = (tid & 15) * 4;
    for (int nn = n; nn < 64; nn += 16) {
        unsigned p0 = (unsigned)bf16rne(tile[kq + 0][nn]) |
                      ((unsigned)bf16rne(tile[kq + 1][nn]) << 16);
        unsigned p1 = (unsigned)bf16rne(tile[kq + 2][nn]) |
                      ((unsigned)bf16rne(tile[kq + 3][nn]) << 16);
        unsigned* dst = (unsigned*)&wbT[(size_t)(n0 + nn) * 256 + k0 + kq];
        dst[0] = p0; dst[1] = p1;
    }
}

// atom_gen = hd(A,256)bf16 @ wbT^T + ad2_b via MFMA 16x16x32 bf16.
// Block: 256 thr = 4 waves; tile 64m x 64n; K=256.
// v2: A-tile read DIRECT from global (L2-resident; zero inter-wave reuse, so
// LDS staging of it bought nothing). Only B (4x wave reuse) stays in LDS,
// staged with dwordx4. LDS 67.6KB -> 33.8KB => 4 blocks/CU (was 2).
#define LSTR 264   // shorts per LDS row (256 + 8 pad)
__global__ __launch_bounds__(256) void k_ad2m(const unsigned short* __restrict__ hdb,
                                              const unsigned short* __restrict__ wbT,
                                              const float* __restrict__ bias,
                                              float* __restrict__ out, int A) {
    __shared__ unsigned short wt[64 * LSTR];
    int tid = threadIdx.x;
    int m0 = blockIdx.x * 64;
    int n0 = blockIdx.y * 64;

    // stage B tile: 64 rows x 256 shorts = 32 KB, 16 B per thread per iter.
    // flat chunk index over 64 rows x 32 chunks(8 shorts) = 2048 -> 8 iters.
    {
        const short8v* src = (const short8v*)(wbT + (size_t)n0 * 256);
#pragma unroll
        for (int i = 0; i < 8; ++i) {
            int flat = tid + 256 * i;
            int row = flat >> 5, ch = flat & 31;
            short8v v = src[flat];               // = row*32 + ch
            *(short8v*)&wt[row * LSTR + ch * 8] = v;
        }
    }
    __syncthreads();

    int wv = tid >> 6, lane = tid & 63;
    int rc = lane & 15;
    int koff = (lane >> 4) * 8;
    float4v acc[4];
#pragma unroll
    for (int i = 0; i < 4; ++i) acc[i] = (float4v){0.f, 0.f, 0.f, 0.f};

    // A fragments straight from global (hd buffer is RECCAP rows, so rows
    // >= A read in-bounds garbage; stores below are guarded by m < A, and a
    // NaN in A-row i only pollutes D-row i which is never stored).
    const short* ha = (const short*)hdb + (size_t)(m0 + wv * 16 + rc) * 256 + koff;
#pragma unroll
    for (int s = 0; s < 8; ++s) {
        short8v a = *(const short8v*)(ha + s * 32);
#pragma unroll
        for (int nt = 0; nt < 4; ++nt) {
            short8v b = *(const short8v*)((const short*)&wt[(nt * 16 + rc) * LSTR + s * 32 + koff]);
            acc[nt] = __builtin_amdgcn_mfma_f32_16x16x32_bf16(a, b, acc[nt], 0, 0, 0);
        }
    }

    int quad = lane >> 4;
#pragma unroll
    for (int nt = 0; nt < 4; ++nt) {
        int n = n0 + nt * 16 + rc;
        float bb = bias[n];
#pragma unroll
        for (int r = 0; r < 4; ++r) {
            int m = m0 + wv * 16 + quad * 4 + r;
            if (m < A) out[(size_t)m * 7680 + n] = acc[nt][r] + bb;
        }
    }
}

// decoder: 4 waves/block, one n per wave; weights staged transposed in LDS.
__global__ __launch_bounds__(256) void k_decoder(const float* __restrict__ bridge,
                          const float* __restrict__ d1w, const float* __restrict__ d1b,
                          const float* __restrict__ d2w, const float* __restrict__ d2b,
                          float* __restrict__ out) {
    __shared__ float d1wt[16 * 5 * 33];   // (c*5+kk)*33 + o
    __shared__ float d2wt[576];           // (ic*3+dk)*6 + oc
    __shared__ float d1bs[32], d2bs[8];
    __shared__ float brs[4][64];
    __shared__ float gs[4][640];
    int tid = threadIdx.x;
    for (int i = tid; i < 2560; i += 256) {
        int c = i / 160, r = i - c * 160, o = r / 5, kk = r - o * 5;
        d1wt[(c * 5 + kk) * 33 + o] = d1w[i];
    }
    for (int i = tid; i < 576; i += 256) {
        int oc = i / 96, r = i - oc * 96, ic = r / 3, dk = r - ic * 3;
        d2wt[(ic * 3 + dk) * 6 + oc] = d2w[i];
    }
    if (tid < 32) d1bs[tid] = d1b[tid];
    else if (tid < 38) d2bs[tid - 32] = d2b[tid - 32];
    int wv = tid >> 6, lane = tid & 63;
    int n = blockIdx.x * 4 + wv;
    brs[wv][lane] = bridge[(size_t)n * 64 + lane];
    __syncthreads();
    for (int idx = lane; idx < 640; idx += 64) {
        int o = idx / 20, p = idx - o * 20, i = p / 5, kk = p - i * 5;
        float acc = d1bs[o];
#pragma unroll
        for (int c = 0; c < 16; ++c) acc += brs[wv][c * 4 + i] * d1wt[(c * 5 + kk) * 33 + o];
        gs[wv][idx] = fmaxf(acc, 0.f);
    }
    __syncthreads();
    for (int idx = lane; idx < 120; idx += 64) {
        int oc = idx / 20, t = idx - oc * 20;
        float acc = d2bs[oc];
        for (int ic = 0; ic < 32; ++ic) {
            const float* gr = &gs[wv][ic * 20];
            float a0 = (t >= 1) ? gr[t - 1] : 0.f;
            float a1 = gr[t];
            float a2 = (t + 1 < 20) ? gr[t + 1] : 0.f;
            acc += a0 * d2wt[(ic * 3 + 0) * 6 + oc]
                 + a1 * d2wt[(ic * 3 + 1) * 6 + oc]
                 + a2 * d2wt[(ic * 3 + 2) * 6 + oc];
        }
        out[(size_t)n * 120 + idx] = acc;
    }
}

// ---------------------------------------------------------------------------
extern "C" void kernel_launch(void* const* d_in, const int* in_sizes, int n_in,
                              void* d_out, int out_size, void* d_ws, size_t ws_size,
                              hipStream_t stream) {
    const float* x        = (const float*)d_in[0];
    const float* imu_mask = (const float*)d_in[1];
    const float* c1_w = (const float*)d_in[3];
    const float* c1_b = (const float*)d_in[4];
    const float* c2_w = (const float*)d_in[5];
    const float* c2_b = (const float*)d_in[6];
    const float* c3_w = (const float*)d_in[7];
    const float* c3_b = (const float*)d_in[8];
    const float* br_w = (const float*)d_in[9];
    const float* br_b = (const float*)d_in[10];
    const float* f1_w = (const float*)d_in[11];
    const float* f1_b = (const float*)d_in[12];
    const float* f2_w = (const float*)d_in[13];
    const float* f2_b = (const float*)d_in[14];
    const float* d1_w = (const float*)d_in[15];
    const float* d1_b = (const float*)d_in[16];
    const float* d2_w = (const float*)d_in[17];
    const float* d2_b = (const float*)d_in[18];
    const float* ae1_w = (const float*)d_in[19];
    const float* ae1_b = (const float*)d_in[20];
    const float* ae2_w = (const float*)d_in[21];
    const float* ae2_b = (const float*)d_in[22];
    const float* ae3_w = (const float*)d_in[23];
    const float* ae3_b = (const float*)d_in[24];
    const float* ad1_w = (const float*)d_in[25];
    const float* ad1_b = (const float*)d_in[26];
    const float* ad2_w = (const float*)d_in[27];
    const float* ad2_b = (const float*)d_in[28];

    // A from out_size: out_size = 6,176,768 + 23,040*A
    int A = (out_size - 6176768) / 23040;
    if (A < 1) A = 1;

    float* out = (float*)d_out;
    size_t o_imu_gen  = 0;
    size_t o_atom_gen = 1966080;
    size_t o_mask     = o_atom_gen + (size_t)A * 7680;
    size_t o_atoms    = o_mask + (size_t)A * 7680;
    size_t o_resh     = o_atoms + (size_t)A * 7680;
    size_t o_fin      = o_resh + 1048576;
    size_t o_fc       = o_fin + 1048576;
    size_t o_fmask    = o_fc + 1048576;
    size_t o_loss     = o_fmask + 1048576;

    // workspace layout (float units)
    float* wsf = (float*)d_ws;
    int*   wsi = (int*)d_ws;
    const size_t W_BRIDGE = 0;                       // 1,048,576
    const size_t W_FEAT   = W_BRIDGE + 1048576;      // 4,194,304
    const size_t W_SCORES = W_FEAT + 4194304;        // 16,384
    const size_t W_CUTOFF = W_SCORES + 16384;        // 64
    const size_t MW       = W_CUTOFF + 64;           // meta (int units)
    int* counts   = wsi + MW;
    int* total    = wsi + MW + 128;
    int* segs     = wsi + MW + 192;                          // BS*SEGSTRIDE
    int* rec_b    = wsi + MW + 192 + BS * SEGSTRIDE;
    int* rec_last = rec_b + RECCAP;
    int* rec_e    = rec_last + RECCAP;
    size_t HD_OFF = MW + 192 + BS * SEGSTRIDE + 3 * RECCAP;
    unsigned short* hd  = (unsigned short*)(wsf + HD_OFF);           // RECCAP*256 bf16
    unsigned short* wbT = (unsigned short*)(wsf + HD_OFF + (size_t)RECCAP * 128);  // 7680*256 bf16

    hipMemsetAsync(rec_b, 0, 3 * RECCAP * sizeof(int), stream);

    const int T = 256;
    // independent of everything downstream — run first
    dim3 gt(120, 4);
    k_wtrans<<<gt, 256, 0, stream>>>(ad2_w, wbT);
    k_encoder<<<NWIN / 4, 256, 0, stream>>>(x, c1_w, c1_b, c2_w, c2_b, c3_w, c3_b,
                                            br_w, br_b, wsf + W_BRIDGE,
                                            out + o_resh, out + o_fin);
    k_f1<<<NWIN, 256, 0, stream>>>(wsf + W_BRIDGE, f1_w, f1_b, wsf + W_FEAT);
    k_f2_loss<<<NWIN, 64, 0, stream>>>(wsf + W_FEAT, wsf + W_BRIDGE, f2_w, f2_b, imu_mask,
                                       out + o_fc, out + o_fmask, out + o_loss, wsf + W_SCORES);
    k_select<<<1, 256, 0, stream>>>(wsf + W_SCORES, wsf + W_CUTOFF);
    k_segments<<<1, 128, 0, stream>>>(out + o_loss, wsf + W_CUTOFF, segs, counts);
    k_emit<<<1, 128, 0, stream>>>(counts, segs, rec_b, rec_last, rec_e, total);
    k_gather_atoms<<<(A * 7680 + T - 1) / T, T, 0, stream>>>(rec_b, rec_last, rec_e, x,
                                                             out + o_atoms, out + o_mask, A);
    k_ae2<<<(A + 7) / 8, 256, 0, stream>>>(rec_b, rec_last, rec_e, wsf + W_BRIDGE,
                                           ae1_w, ae1_b, ae2_w, ae2_b, ae3_w, ae3_b,
                                           ad1_w, ad1_b, hd, A);
    dim3 g2((A + 63) / 64, 120);
    k_ad2m<<<g2, 256, 0, stream>>>(hd, wbT, ad2_b, out + o_atom_gen, A);
    k_decoder<<<NWIN / 4, 256, 0, stream>>>(wsf + W_BRIDGE, d1_w, d1_b, d2_w, d2_b,
                                            out + o_imu_gen);
}

// Round 2
// 893.070 us; speedup vs baseline: 1.1903x; 1.0090x over previous
//
#include <hip/hip_runtime.h>
#include <math.h>

// ---------------------------------------------------------------------------
// AtomicHAR pipeline. fp32 everywhere except the post-selection ad2 GEMM
// (bf16 MFMA — cannot affect segment selection; tolerance 9.9e-2 vs ~3e-3 err).
// bs=128 seq=128 C=6 L=20 N=16384 D=64 H=256 MAL=10 Wtot=1280
// ---------------------------------------------------------------------------

#define NWIN 16384   // bs*seq
#define SEQ  128
#define BS   128
#define KSEL 3276    // int(16384*0.2)
#define SEGSTRIDE 160    // worst-case segments per batch ~140
#define RECCAP 18432     // worst-case total segments

typedef __attribute__((ext_vector_type(8))) short short8v;
typedef __attribute__((ext_vector_type(4))) float float4v;

__device__ inline unsigned short bf16rne(float f) {
    unsigned u = __float_as_uint(f);
    unsigned r = u + 0x7FFFu + ((u >> 16) & 1u);
    return (unsigned short)(r >> 16);
}

// ---------------- fused encoder: conv1+pool, conv2+pool, conv3+pool, bridge --
__global__ __launch_bounds__(256) void k_encoder(
        const float* __restrict__ x,
        const float* __restrict__ c1w, const float* __restrict__ c1b,
        const float* __restrict__ c2w, const float* __restrict__ c2b,
        const float* __restrict__ c3w, const float* __restrict__ c3b,
        const float* __restrict__ brw, const float* __restrict__ brb,
        float* __restrict__ bridge, float* __restrict__ out_resh,
        float* __restrict__ out_fin) {
    __shared__ float c1wt[288];    // (ic*3+dk)*16 + oc
    __shared__ float c2wt[1536];   // (ic*3+dk)*32 + oc
    __shared__ float c3wt[3072];   // (ic*3+dk)*32 + oc
    __shared__ float brws[4096];   // i*64 + d
    __shared__ float c1bs[16], c2bs[32], c3bs[32], brbs[64];
    __shared__ float xs[4][128], c1s[4][160], c2s[4][160], c3s[4][64];

    int tid = threadIdx.x;
    for (int i = tid; i < 288; i += 256) {
        int oc = i / 18, r = i - oc * 18, ic = r / 3, dk = r - ic * 3;
        c1wt[(ic * 3 + dk) * 16 + oc] = c1w[i];
    }
    for (int i = tid; i < 1536; i += 256) {
        int oc = i / 48, r = i - oc * 48, ic = r / 3, dk = r - ic * 3;
        c2wt[(ic * 3 + dk) * 32 + oc] = c2w[i];
    }
    for (int i = tid; i < 3072; i += 256) {
        int oc = i / 96, r = i - oc * 96, ic = r / 3, dk = r - ic * 3;
        c3wt[(ic * 3 + dk) * 32 + oc] = c3w[i];
    }
    for (int i = tid; i < 4096; i += 256) brws[i] = brw[i];
    if (tid < 16) c1bs[tid] = c1b[tid];
    else if (tid < 48) c2bs[tid - 16] = c2b[tid - 16];
    else if (tid < 80) c3bs[tid - 48] = c3b[tid - 48];
    else if (tid < 144) brbs[tid - 80] = brb[tid - 80];

    int wv = tid >> 6, lane = tid & 63;
    int n = blockIdx.x * 4 + wv;
    const float* xr = x + (size_t)n * 120;
    if (lane < 60) ((float2*)&xs[wv][0])[lane] = ((const float2*)xr)[lane];
    __syncthreads();

    // conv1
    {
        int oc = lane >> 2, tg = lane & 3;
        float bb = c1bs[oc];
        float acc[3][2];
#pragma unroll
        for (int j = 0; j < 3; ++j) { acc[j][0] = bb; acc[j][1] = bb; }
        for (int ic = 0; ic < 6; ++ic) {
            float w0 = c1wt[(ic * 3 + 0) * 16 + oc];
            float w1 = c1wt[(ic * 3 + 1) * 16 + oc];
            float w2 = c1wt[(ic * 3 + 2) * 16 + oc];
            const float* ar = &xs[wv][ic * 20];
#pragma unroll
            for (int j = 0; j < 3; ++j) {
                int t = tg + 4 * j;
                if (t < 10) {
#pragma unroll
                    for (int q = 0; q < 2; ++q) {
                        int p = 2 * t + q;
                        float a0 = (p >= 1) ? ar[p - 1] : 0.f;
                        float a1 = ar[p];
                        float a2 = (p + 1 < 20) ? ar[p + 1] : 0.f;
                        acc[j][q] += a0 * w0 + a1 * w1 + a2 * w2;
                    }
                }
            }
        }
#pragma unroll
        for (int j = 0; j < 3; ++j) {
            int t = tg + 4 * j;
            if (t < 10) c1s[wv][oc * 10 + t] = fmaxf(fmaxf(acc[j][0], acc[j][1]), 0.f);
        }
    }
    __syncthreads();

    // conv2
    {
        int oc = lane >> 1, tg = lane & 1;
        float bb = c2bs[oc];
        float acc[3][2];
#pragma unroll
        for (int j = 0; j < 3; ++j) { acc[j][0] = bb; acc[j][1] = bb; }
        for (int ic = 0; ic < 16; ++ic) {
            float w0 = c2wt[(ic * 3 + 0) * 32 + oc];
            float w1 = c2wt[(ic * 3 + 1) * 32 + oc];
            float w2 = c2wt[(ic * 3 + 2) * 32 + oc];
            const float* ar = &c1s[wv][ic * 10];
#pragma unroll
            for (int j = 0; j < 3; ++j) {
                int t = tg + 2 * j;
                if (t < 5) {
#pragma unroll
                    for (int q = 0; q < 2; ++q) {
                        int p = 2 * t + q;
                        float a0 = (p >= 1) ? ar[p - 1] : 0.f;
                        float a1 = ar[p];
                        float a2 = (p + 1 < 10) ? ar[p + 1] : 0.f;
                        acc[j][q] += a0 * w0 + a1 * w1 + a2 * w2;
                    }
                }
            }
        }
#pragma unroll
        for (int j = 0; j < 3; ++j) {
            int t = tg + 2 * j;
            if (t < 5) c2s[wv][oc * 5 + t] = fmaxf(fmaxf(acc[j][0], acc[j][1]), 0.f);
        }
    }
    __syncthreads();

    // conv3
    {
        int oc = lane >> 1, tp = lane & 1;
        float bb = c3bs[oc];
        float acc0 = bb, acc1 = bb;
        for (int ic = 0; ic < 32; ++ic) {
            float w0 = c3wt[(ic * 3 + 0) * 32 + oc];
            float w1 = c3wt[(ic * 3 + 1) * 32 + oc];
            float w2 = c3wt[(ic * 3 + 2) * 32 + oc];
            const float* ar = &c2s[wv][ic * 5];
            {
                int p = 2 * tp;
                float a0 = (p >= 1) ? ar[p - 1] : 0.f;
                acc0 += a0 * w0 + ar[p] * w1 + ar[p + 1] * w2;
            }
            {
                int p = 2 * tp + 1;
                acc1 += ar[p - 1] * w0 + ar[p] * w1 + ((p + 1 < 5) ? ar[p + 1] : 0.f) * w2;
            }
        }
        c3s[wv][lane] = fmaxf(fmaxf(acc0, acc1), 0.f);
    }
    __syncthreads();

    // bridge
    {
        float acc = brbs[lane];
        for (int i = 0; i < 64; ++i) acc += c3s[wv][i] * brws[i * 64 + lane];
        float v = 1.f / (1.f + expf(-acc));
        size_t o = (size_t)n * 64 + lane;
        bridge[o] = v; out_resh[o] = v; out_fin[o] = v;
    }
}

// ---------------- fused forecaster: feat = relu(shft@w1+b1); fc = feat@w2+b2;
// loss/scores. One wave per window, 8 windows/wave, both weights LDS-staged
// once per block (128 KB). Accumulation orders bit-identical to the previous
// separate kernels (d sequential, h sequential, same shfl_down tree).
__global__ __launch_bounds__(512) void k_forecast(
        const float* __restrict__ bridge,
        const float* __restrict__ w1, const float* __restrict__ b1,
        const float* __restrict__ w2, const float* __restrict__ b2,
        const float* __restrict__ imu_mask,
        float* __restrict__ out_fc, float* __restrict__ out_fmask,
        float* __restrict__ out_loss, float* __restrict__ scores) {
    __shared__ float w1s[16384];   // d*256 + h
    __shared__ float w2s[16384];   // h*64 + d
    __shared__ float b1s[256], b2s[64];
    __shared__ float fts[8][256];  // per-wave feat buffer

    int tid = threadIdx.x;
    {
        const float4* s1 = (const float4*)w1;
        const float4* s2 = (const float4*)w2;
        float4* d1 = (float4*)w1s;
        float4* d2 = (float4*)w2s;
        for (int i = tid; i < 4096; i += 512) { d1[i] = s1[i]; d2[i] = s2[i]; }
    }
    if (tid < 256) b1s[tid] = b1[tid];
    else if (tid < 320) b2s[tid - 256] = b2[tid - 256];
    __syncthreads();

    int wv = tid >> 6, lane = tid & 63;
    int nbase = blockIdx.x * 64 + wv * 8;
#pragma unroll 1
    for (int i = 0; i < 8; ++i) {
        int n = nbase + i;
        int s = n & (SEQ - 1);
        // feat: lane owns h = lane + 64*j
        float acc[4];
#pragma unroll
        for (int j = 0; j < 4; ++j) acc[j] = b1s[lane + 64 * j];
        if (s > 0) {
            float brv = bridge[(size_t)(n - 1) * 64 + lane];
#pragma unroll 4
            for (int d = 0; d < 64; ++d) {
                float bd = __shfl(brv, d);
#pragma unroll
                for (int j = 0; j < 4; ++j)
                    acc[j] += bd * w1s[d * 256 + lane + 64 * j];
            }
        }
#pragma unroll
        for (int j = 0; j < 4; ++j) fts[wv][lane + 64 * j] = fmaxf(acc[j], 0.f);
        // same-wave LDS RAW: ordered by compiler-inserted lgkmcnt, no barrier.
        float fa = b2s[lane];
#pragma unroll 8
        for (int h = 0; h < 256; ++h) fa += fts[wv][h] * w2s[h * 64 + lane];
        out_fc[(size_t)n * 64 + lane] = fa;
        float mval = (s == 0) ? 0.f : imu_mask[(size_t)n * 120];
        out_fmask[(size_t)n * 64 + lane] = mval;
        float diff = (fa - bridge[(size_t)n * 64 + lane]) * mval;
        float sq = diff * diff;
#pragma unroll
        for (int off = 32; off; off >>= 1) sq += __shfl_down(sq, off);
        if (lane == 0) {
            float loss = sq * (1.f / 64.f);
            out_loss[n] = loss;
            scores[n] = loss * mval;
        }
    }
}

// ---------------- fused post-selection: exact k-th radix select (per-wave
// histograms to cut same-address LDS-atomic serialization), per-batch
// segmentation with gap-fill, prefix scan + record emit. 1 block x 256.
__global__ __launch_bounds__(256) void k_postsel(
        const float* __restrict__ scores, const float* __restrict__ loss,
        int* __restrict__ rec_b, int* __restrict__ rec_last,
        int* __restrict__ rec_e, int* __restrict__ total_out) {
    __shared__ unsigned hist[4][256];
    __shared__ unsigned sh_prefix;
    __shared__ int sh_k;
    __shared__ int segs[BS][SEGSTRIDE];   // 80 KB
    __shared__ int counts[BS];
    __shared__ int offs[BS + 1];
    int tid = threadIdx.x, wv = tid >> 6;
    if (tid == 0) { sh_prefix = 0u; sh_k = KSEL; }
    __syncthreads();
    for (int shift = 24; shift >= 0; shift -= 8) {
#pragma unroll
        for (int w = 0; w < 4; ++w) hist[w][tid] = 0u;
        __syncthreads();
        unsigned prefix = sh_prefix;
        unsigned pmask = (shift == 24) ? 0u : (0xFFFFFFFFu << (shift + 8));
        for (int i = tid; i < NWIN; i += 256) {
            unsigned u = __float_as_uint(scores[i]);
            if ((u & pmask) == prefix) atomicAdd(&hist[wv][(u >> shift) & 255u], 1u);
        }
        __syncthreads();
        if (tid == 0) {
            int kk = sh_k;
            for (int bin = 255; bin >= 0; --bin) {
                int c = (int)(hist[0][bin] + hist[1][bin] + hist[2][bin] + hist[3][bin]);
                if (kk <= c) { sh_prefix = prefix | ((unsigned)bin << shift); sh_k = kk; break; }
                kk -= c;
            }
        }
        __syncthreads();
    }
    float cutoff = __uint_as_float(sh_prefix);

    if (tid < BS) {
        int b = tid;
        int* my = segs[b];
        int cnt = 0, prev = 0;
        bool has = false;
        for (int s = 0; s < SEQ; ++s) {
            if (loss[b * SEQ + s] > cutoff) {
                if (has) {
                    if (s - prev > 10) {
                        my[cnt++] = prev;
                        int cur = prev;
                        while (cur < s) {
                            cur += 10;
                            if (cur >= s) break;
                            my[cnt++] = cur;
                        }
                    } else {
                        my[cnt++] = prev;
                    }
                }
                has = true; prev = s;
            }
        }
        if (has) my[cnt++] = prev;
        counts[b] = cnt;
    }
    __syncthreads();
    if (tid == 0) {
        int acc = 0;
        for (int b = 0; b < BS; ++b) { offs[b] = acc; acc += counts[b]; }
        offs[BS] = acc;
        *total_out = acc;
        if (acc == 0) { rec_b[0] = 0; rec_last[0] = 0; rec_e[0] = 0; }  // fallback dummy
    }
    __syncthreads();
    if (tid < BS) {
        int b = tid;
        int o = offs[b], c = counts[b];
        for (int j = 0; j < c; ++j) {
            int idx = o + j;
            if (idx >= RECCAP) break;
            rec_b[idx] = b;
            rec_last[idx] = (j > 0) ? segs[b][j - 1] : 0;
            rec_e[idx] = segs[b][j];
        }
    }
}

// imu_atoms + mask: (A, 6, 1280)
__global__ void k_gather_atoms(const int* __restrict__ rec_b, const int* __restrict__ rec_last,
                               const int* __restrict__ rec_e, const float* __restrict__ x,
                               float* __restrict__ out_atoms, float* __restrict__ out_mask, int A) {
    int gid = blockIdx.x * blockDim.x + threadIdx.x;
    if (gid >= A * 7680) return;
    int a = gid / 7680, rem = gid % 7680, c = rem / 1280, wcol = rem % 1280;
    int b = rec_b[a], last = rec_last[a], e = rec_e[a];
    int W = (e - last) * 20;
    int sc = wcol - (1280 - W);
    float v = 0.f, m = 0.f;
    if (sc >= 0 && sc < W) {
        int t = sc / 20, l = sc % 20;
        v = x[((b * SEQ + last + t) * 6 + c) * 20 + l];
        m = 1.f;
    }
    out_atoms[gid] = v;
    out_mask[gid] = m;
}

// ---------------- autoencoder, batched: 8 segments/block, 256 threads -------
// LDS-staged transposed weights; ae1 p-loop register-hoisted; ad1 joint.
__global__ __launch_bounds__(256) void k_ae2(
        const int* __restrict__ rec_b, const int* __restrict__ rec_last,
        const int* __restrict__ rec_e, const float* __restrict__ bridge,
        const float* __restrict__ ae1w, const float* __restrict__ ae1b,
        const float* __restrict__ ae2w, const float* __restrict__ ae2b,
        const float* __restrict__ ae3w, const float* __restrict__ ae3b,
        const float* __restrict__ ad1w, const float* __restrict__ ad1b,
        unsigned short* __restrict__ hd, int A) {
    __shared__ float ae1wt[6144];   // (ic*3+dk)*32 + o   (o<32, ic<64)
    __shared__ float ae2wt[1536];   // (ic*3+dk)*16 + c   (c<16, ic<32)
    __shared__ float ae3ws[2560];   // i*32 + o
    __shared__ float ae1bs[32], ae2bs[16], ae3bs[32];
    __shared__ float af_s[8][640];  // [seg][ic*10+r]
    __shared__ float c1p[8][160];   // pooled+relu ae1 out [seg][o*5+t]
    __shared__ float h2s[8][80];    // [seg][c*5+t]
    __shared__ float embs[32][8];   // [o][seg]

    int tid = threadIdx.x;
    int a0 = blockIdx.x * 8;

    // ---- stage weights (transposed) ----
    for (int i = tid; i < 6144; i += 256) {
        int o = i / 192, r = i - o * 192, ic = r / 3, dk = r - ic * 3;
        ae1wt[(ic * 3 + dk) * 32 + o] = ae1w[i];
    }
    for (int i = tid; i < 1536; i += 256) {
        int c = i / 96, r = i - c * 96, ic = r / 3, dk = r - ic * 3;
        ae2wt[(ic * 3 + dk) * 16 + c] = ae2w[i];
    }
    for (int i = tid; i < 2560; i += 256) ae3ws[i] = ae3w[i];
    if (tid < 32) ae1bs[tid] = ae1b[tid];
    else if (tid < 48) ae2bs[tid - 32] = ae2b[tid - 32];
    else if (tid < 80) ae3bs[tid - 48] = ae3b[tid - 48];

    // ---- gather af from bridge (each wave: its 2 segments) ----
    int wv = tid >> 6, lane = tid & 63;
#pragma unroll
    for (int sg = 0; sg < 2; ++sg) {
        int seg = wv * 2 + sg;
        int ac = a0 + seg; if (ac > A - 1) ac = A - 1;
        int b = rec_b[ac], last = rec_last[ac], e = rec_e[ac];
#pragma unroll
        for (int r = 0; r < 10; ++r) {
            int src = e - 10 + r;
            float v = (src >= last) ? bridge[(size_t)(b * SEQ + src) * 64 + lane] : 0.f;
            af_s[seg][lane * 10 + r] = v;
        }
    }
    __syncthreads();

    // ---- ae1 conv + relu + pool: seg = wv*2 + (lane>>5), o = lane&31 ----
    {
        int seg = wv * 2 + (lane >> 5);
        int o = lane & 31;
        const float* afl = af_s[seg];
        float bb = ae1bs[o];
        float acc[10];
#pragma unroll
        for (int p = 0; p < 10; ++p) acc[p] = bb;
        for (int ic = 0; ic < 64; ++ic) {
            float av[10];
#pragma unroll
            for (int r = 0; r < 10; ++r) av[r] = afl[ic * 10 + r];  // broadcast
            float w0 = ae1wt[(ic * 3 + 0) * 32 + o];
            float w1 = ae1wt[(ic * 3 + 1) * 32 + o];
            float w2 = ae1wt[(ic * 3 + 2) * 32 + o];
            acc[0] += av[0] * w1 + av[1] * w2;
#pragma unroll
            for (int p = 1; p < 9; ++p)
                acc[p] += av[p - 1] * w0 + av[p] * w1 + av[p + 1] * w2;
            acc[9] += av[8] * w0 + av[9] * w1;
        }
#pragma unroll
        for (int t = 0; t < 5; ++t)
            c1p[seg][o * 5 + t] = fmaxf(fmaxf(acc[2 * t], acc[2 * t + 1]), 0.f);
    }
    __syncthreads();

    // ---- ae2 conv + relu: seg = wv*2+(lane>>5); c = (lane&31)>>1, th = lane&1 ----
    {
        int seg = wv * 2 + (lane >> 5);
        int c = (lane & 31) >> 1, th = lane & 1;
        const float* cp = c1p[seg];
        float bb = ae2bs[c];
        float acc2[3] = {bb, bb, bb};
        for (int ic = 0; ic < 32; ++ic) {
            float m[5];
#pragma unroll
            for (int t = 0; t < 5; ++t) m[t] = cp[ic * 5 + t];  // broadcast
            float w0 = ae2wt[(ic * 3 + 0) * 16 + c];
            float w1 = ae2wt[(ic * 3 + 1) * 16 + c];
            float w2 = ae2wt[(ic * 3 + 2) * 16 + c];
#pragma unroll
            for (int j = 0; j < 3; ++j) {
                int t = th + 2 * j;
                if (t < 5) {
                    float am1 = (t > 0) ? m[t - 1] : 0.f;
                    float ap1 = (t < 4) ? m[t + 1] : 0.f;
                    acc2[j] += am1 * w0 + m[t] * w1 + ap1 * w2;
                }
            }
        }
#pragma unroll
        for (int j = 0; j < 3; ++j) {
            int t = th + 2 * j;
            if (t < 5) h2s[seg][c * 5 + t] = fmaxf(acc2[j], 0.f);
        }
    }
    __syncthreads();

    // ---- ae3: emb(32) per seg: seg = wv*2+(lane>>5), o = lane&31 ----
    {
        int seg = wv * 2 + (lane >> 5);
        int o = lane & 31;
        float acc = ae3bs[o];
        const float* hh = h2s[seg];
        for (int i = 0; i < 80; ++i) acc += hh[i] * ae3ws[i * 32 + o];
        embs[o][seg] = acc;   // no relu on emb
    }
    __syncthreads();

    // ---- ad1 joint: thread tid owns output column idx for ALL 8 segs ----
    {
        int idx = tid;
        float bb = ad1b[idx];
        float acc[8];
#pragma unroll
        for (int s = 0; s < 8; ++s) acc[s] = bb;
        for (int o = 0; o < 32; ++o) {
            float wq = ad1w[o * 256 + idx];   // coalesced, reused 8x
#pragma unroll
            for (int s = 0; s < 8; ++s) acc[s] += embs[o][s] * wq;
        }
#pragma unroll
        for (int s = 0; s < 8; ++s) {
            int a = a0 + s;
            if (a < A) hd[(size_t)a * 256 + idx] = bf16rne(fmaxf(acc[s], 0.f));
        }
    }
}

// transpose + bf16-cast ad2_w (256 x 7680, row-major) -> wbT (7680 x 256, n-major)
__global__ __launch_bounds__(256) void k_wtrans(const float* __restrict__ w,
                                                unsigned short* __restrict__ wbT) {
    __shared__ float tile[64][65];
    int n0 = blockIdx.x * 64, k0 = blockIdx.y * 64;
    int tid = threadIdx.x;
    int c = tid & 63;
    for (int r = tid >> 6; r < 64; r += 4)
        tile[r][c] = w[(size_t)(k0 + r) * 7680 + n0 + c];
    __syncthreads();
    int n = tid >> 4, kq = (tid & 15) * 4;
    for (int nn = n; nn < 64; nn += 16) {
        unsigned p0 = (unsigned)bf16rne(tile[kq + 0][nn]) |
                      ((unsigned)bf16rne(tile[kq + 1][nn]) << 16);
        unsigned p1 = (unsigned)bf16rne(tile[kq + 2][nn]) |
                      ((unsigned)bf16rne(tile[kq + 3][nn]) << 16);
        unsigned* dst = (unsigned*)&wbT[(size_t)(n0 + nn) * 256 + k0 + kq];
        dst[0] = p0; dst[1] = p1;
    }
}

// atom_gen = hd(A,256)bf16 @ wbT^T + ad2_b via MFMA 16x16x32 bf16.
// Block: 256 thr = 4 waves; tile 64m x 64n; K=256.
// A-tile read DIRECT from global (L2-resident; zero inter-wave reuse).
// Only B (4x wave reuse) stays in LDS, staged with dwordx4.
#define LSTR 264   // shorts per LDS row (256 + 8 pad)
__global__ __launch_bounds__(256) void k_ad2m(const unsigned short* __restrict__ hdb,
                                              const unsigned short* __restrict__ wbT,
                                              const float* __restrict__ bias,
                                              float* __restrict__ out, int A) {
    __shared__ unsigned short wt[64 * LSTR];
    int tid = threadIdx.x;
    int m0 = blockIdx.x * 64;
    int n0 = blockIdx.y * 64;

    {
        const short8v* src = (const short8v*)(wbT + (size_t)n0 * 256);
#pragma unroll
        for (int i = 0; i < 8; ++i) {
            int flat = tid + 256 * i;
            int row = flat >> 5, ch = flat & 31;
            short8v v = src[flat];
            *(short8v*)&wt[row * LSTR + ch * 8] = v;
        }
    }
    __syncthreads();

    int wv = tid >> 6, lane = tid & 63;
    int rc = lane & 15;
    int koff = (lane >> 4) * 8;
    float4v acc[4];
#pragma unroll
    for (int i = 0; i < 4; ++i) acc[i] = (float4v){0.f, 0.f, 0.f, 0.f};

    const short* ha = (const short*)hdb + (size_t)(m0 + wv * 16 + rc) * 256 + koff;
#pragma unroll
    for (int s = 0; s < 8; ++s) {
        short8v a = *(const short8v*)(ha + s * 32);
#pragma unroll
        for (int nt = 0; nt < 4; ++nt) {
            short8v b = *(const short8v*)((const short*)&wt[(nt * 16 + rc) * LSTR + s * 32 + koff]);
            acc[nt] = __builtin_amdgcn_mfma_f32_16x16x32_bf16(a, b, acc[nt], 0, 0, 0);
        }
    }

    int quad = lane >> 4;
#pragma unroll
    for (int nt = 0; nt < 4; ++nt) {
        int n = n0 + nt * 16 + rc;
        float bb = bias[n];
#pragma unroll
        for (int r = 0; r < 4; ++r) {
            int m = m0 + wv * 16 + quad * 4 + r;
            if (m < A) out[(size_t)m * 7680 + n] = acc[nt][r] + bb;
        }
    }
}

// decoder: 4 waves/block, one n per wave; weights staged transposed in LDS.
__global__ __launch_bounds__(256) void k_decoder(const float* __restrict__ bridge,
                          const float* __restrict__ d1w, const float* __restrict__ d1b,
                          const float* __restrict__ d2w, const float* __restrict__ d2b,
                          float* __restrict__ out) {
    __shared__ float d1wt[16 * 5 * 33];   // (c*5+kk)*33 + o
    __shared__ float d2wt[576];           // (ic*3+dk)*6 + oc
    __shared__ float d1bs[32], d2bs[8];
    __shared__ float brs[4][64];
    __shared__ float gs[4][640];
    int tid = threadIdx.x;
    for (int i = tid; i < 2560; i += 256) {
        int c = i / 160, r = i - c * 160, o = r / 5, kk = r - o * 5;
        d1wt[(c * 5 + kk) * 33 + o] = d1w[i];
    }
    for (int i = tid; i < 576; i += 256) {
        int oc = i / 96, r = i - oc * 96, ic = r / 3, dk = r - ic * 3;
        d2wt[(ic * 3 + dk) * 6 + oc] = d2w[i];
    }
    if (tid < 32) d1bs[tid] = d1b[tid];
    else if (tid < 38) d2bs[tid - 32] = d2b[tid - 32];
    int wv = tid >> 6, lane = tid & 63;
    int n = blockIdx.x * 4 + wv;
    brs[wv][lane] = bridge[(size_t)n * 64 + lane];
    __syncthreads();
    for (int idx = lane; idx < 640; idx += 64) {
        int o = idx / 20, p = idx - o * 20, i = p / 5, kk = p - i * 5;
        float acc = d1bs[o];
#pragma unroll
        for (int c = 0; c < 16; ++c) acc += brs[wv][c * 4 + i] * d1wt[(c * 5 + kk) * 33 + o];
        gs[wv][idx] = fmaxf(acc, 0.f);
    }
    __syncthreads();
    for (int idx = lane; idx < 120; idx += 64) {
        int oc = idx / 20, t = idx - oc * 20;
        float acc = d2bs[oc];
        for (int ic = 0; ic < 32; ++ic) {
            const float* gr = &gs[wv][ic * 20];
            float a0 = (t >= 1) ? gr[t - 1] : 0.f;
            float a1 = gr[t];
            float a2 = (t + 1 < 20) ? gr[t + 1] : 0.f;
            acc += a0 * d2wt[(ic * 3 + 0) * 6 + oc]
                 + a1 * d2wt[(ic * 3 + 1) * 6 + oc]
                 + a2 * d2wt[(ic * 3 + 2) * 6 + oc];
        }
        out[(size_t)n * 120 + idx] = acc;
    }
}

// ---------------------------------------------------------------------------
extern "C" void kernel_launch(void* const* d_in, const int* in_sizes, int n_in,
                              void* d_out, int out_size, void* d_ws, size_t ws_size,
                              hipStream_t stream) {
    const float* x        = (const float*)d_in[0];
    const float* imu_mask = (const float*)d_in[1];
    const float* c1_w = (const float*)d_in[3];
    const float* c1_b = (const float*)d_in[4];
    const float* c2_w = (const float*)d_in[5];
    const float* c2_b = (const float*)d_in[6];
    const float* c3_w = (const float*)d_in[7];
    const float* c3_b = (const float*)d_in[8];
    const float* br_w = (const float*)d_in[9];
    const float* br_b = (const float*)d_in[10];
    const float* f1_w = (const float*)d_in[11];
    const float* f1_b = (const float*)d_in[12];
    const float* f2_w = (const float*)d_in[13];
    const float* f2_b = (const float*)d_in[14];
    const float* d1_w = (const float*)d_in[15];
    const float* d1_b = (const float*)d_in[16];
    const float* d2_w = (const float*)d_in[17];
    const float* d2_b = (const float*)d_in[18];
    const float* ae1_w = (const float*)d_in[19];
    const float* ae1_b = (const float*)d_in[20];
    const float* ae2_w = (const float*)d_in[21];
    const float* ae2_b = (const float*)d_in[22];
    const float* ae3_w = (const float*)d_in[23];
    const float* ae3_b = (const float*)d_in[24];
    const float* ad1_w = (const float*)d_in[25];
    const float* ad1_b = (const float*)d_in[26];
    const float* ad2_w = (const float*)d_in[27];
    const float* ad2_b = (const float*)d_in[28];

    // A from out_size: out_size = 6,176,768 + 23,040*A
    int A = (out_size - 6176768) / 23040;
    if (A < 1) A = 1;

    float* out = (float*)d_out;
    size_t o_imu_gen  = 0;
    size_t o_atom_gen = 1966080;
    size_t o_mask     = o_atom_gen + (size_t)A * 7680;
    size_t o_atoms    = o_mask + (size_t)A * 7680;
    size_t o_resh     = o_atoms + (size_t)A * 7680;
    size_t o_fin      = o_resh + 1048576;
    size_t o_fc       = o_fin + 1048576;
    size_t o_fmask    = o_fc + 1048576;
    size_t o_loss     = o_fmask + 1048576;

    // workspace layout (float units)
    float* wsf = (float*)d_ws;
    int*   wsi = (int*)d_ws;
    const size_t W_BRIDGE = 0;                       // 1,048,576
    const size_t W_FEAT   = W_BRIDGE + 1048576;      // 4,194,304 (now unused)
    const size_t W_SCORES = W_FEAT + 4194304;        // 16,384
    const size_t W_CUTOFF = W_SCORES + 16384;        // 64 (now unused)
    const size_t MW       = W_CUTOFF + 64;           // meta (int units)
    int* counts   = wsi + MW;                        // (unused, layout kept)
    int* total    = wsi + MW + 128;
    int* segs     = wsi + MW + 192;                          // (unused)
    int* rec_b    = wsi + MW + 192 + BS * SEGSTRIDE;
    int* rec_last = rec_b + RECCAP;
    int* rec_e    = rec_last + RECCAP;
    size_t HD_OFF = MW + 192 + BS * SEGSTRIDE + 3 * RECCAP;
    unsigned short* hd  = (unsigned short*)(wsf + HD_OFF);           // RECCAP*256 bf16
    unsigned short* wbT = (unsigned short*)(wsf + HD_OFF + (size_t)RECCAP * 128);  // 7680*256 bf16
    (void)counts; (void)segs;

    hipMemsetAsync(rec_b, 0, 3 * RECCAP * sizeof(int), stream);

    const int T = 256;
    // independent of everything downstream — run first
    dim3 gt(120, 4);
    k_wtrans<<<gt, 256, 0, stream>>>(ad2_w, wbT);
    k_encoder<<<NWIN / 4, 256, 0, stream>>>(x, c1_w, c1_b, c2_w, c2_b, c3_w, c3_b,
                                            br_w, br_b, wsf + W_BRIDGE,
                                            out + o_resh, out + o_fin);
    k_forecast<<<NWIN / 64, 512, 0, stream>>>(wsf + W_BRIDGE, f1_w, f1_b, f2_w, f2_b,
                                              imu_mask, out + o_fc, out + o_fmask,
                                              out + o_loss, wsf + W_SCORES);
    k_postsel<<<1, 256, 0, stream>>>(wsf + W_SCORES, out + o_loss,
                                     rec_b, rec_last, rec_e, total);
    k_gather_atoms<<<(A * 7680 + T - 1) / T, T, 0, stream>>>(rec_b, rec_last, rec_e, x,
                                                             out + o_atoms, out + o_mask, A);
    k_ae2<<<(A + 7) / 8, 256, 0, stream>>>(rec_b, rec_last, rec_e, wsf + W_BRIDGE,
                                           ae1_w, ae1_b, ae2_w, ae2_b, ae3_w, ae3_b,
                                           ad1_w, ad1_b, hd, A);
    dim3 g2((A + 63) / 64, 120);
    k_ad2m<<<g2, 256, 0, stream>>>(hd, wbT, ad2_b, out + o_atom_gen, A);
    k_decoder<<<NWIN / 4, 256, 0, stream>>>(wsf + W_BRIDGE, d1_w, d1_b, d2_w, d2_b,
                                            out + o_imu_gen);
}